// Round 13
// baseline (133.489 us; speedup 1.0000x reference)
//
#include <hip/hip_runtime.h>
#include <math.h>

#define NP 8192
#define NF 16384
#define GQ 4                 // points per thread (live state ~40 VGPR < 63 tier)
#define PPB (256*GQ)         // points per block = 1024
#define NPB (NP/PPB)         // point blocks = 8
#define MAXNFS 1024          // LDS sized for worst case (SPLIT=16)
#define MARGIN 1e-5f         // f32 key abs-error ~2e-6; 5x safety (R6/R12-proven)

#define FOR4(X) X(0) X(1) X(2) X(3)

// ---------------------------------------------------------------------------
// K0: face centers: f64 (cx,cy,cz,|c|^2) for exact d2/repair, f32 copy for
// the fast scan, plus Adagrad clr table. np: c=(v0+v1+v2)/3 in f64.
// ---------------------------------------------------------------------------
__global__ __launch_bounds__(256) void k_centers(const float* __restrict__ mV,
                                                 const int* __restrict__ mF,
                                                 double* __restrict__ ctr,
                                                 float4* __restrict__ ctrf,
                                                 double* __restrict__ clrtab) {
    if (blockIdx.x == 0 && threadIdx.x < 50) {
        clrtab[threadIdx.x] = 0.2 / (1.0 + (double)threadIdx.x * 0.1);
    }
    int f = blockIdx.x * 256 + threadIdx.x;
    if (f >= NF) return;
    int i0 = mF[3*f+0], i1 = mF[3*f+1], i2 = mF[3*f+2];
    double cx = ((double)mV[3*i0+0] + (double)mV[3*i1+0] + (double)mV[3*i2+0]) / 3.0;
    double cy = ((double)mV[3*i0+1] + (double)mV[3*i1+1] + (double)mV[3*i2+1]) / 3.0;
    double cz = ((double)mV[3*i0+2] + (double)mV[3*i1+2] + (double)mV[3*i2+2]) / 3.0;
    double cc = cx*cx + cy*cy + cz*cz;
    ctr[4*f+0] = cx; ctr[4*f+1] = cy; ctr[4*f+2] = cz; ctr[4*f+3] = cc;
    ctrf[f] = make_float4((float)cx, (float)cy, (float)cz, (float)cc);
}

// ---------------------------------------------------------------------------
// K1a: f32 partial 1-NN — R12's exact per-split logic (proven bit-identical
// outputs), reshaped: GQ=4 points/thread so each LDS face-read (12cyc pipe
// op, R12's wall at 41µs/CU) amortizes over ~60cyc of VALU -> VALU-bound.
// Named scalars keep live state ~40 VGPR (< the 63-VGPR squeeze tier that
// caused R6/R8 spills). Per split: top-2, winner idx, ambiguity flag
// (b2-b1<MARGIN) packed into bits 16+ of pidxfl. key = cc - 2 q.c;
// ascending i + strict < = first-min (lex) within split.
// ---------------------------------------------------------------------------
__global__ __launch_bounds__(256) void k_knn_part(const float* __restrict__ qV,
                                                  const float4* __restrict__ ctrf,
                                                  float* __restrict__ pkey,
                                                  int* __restrict__ pidxfl,
                                                  int split, int nfs) {
    __shared__ float4 sh[MAXNFS];
    int g = blockIdx.x / split;   // point block
    int s = blockIdx.x % split;   // face split
    int fbase = s * nfs;

    // stage the split's centers into LDS (coalesced)
    for (int i = threadIdx.x; i < nfs; i += 256) sh[i] = ctrf[fbase + i];

    // 4 points per thread, stride-256 for coalesced q loads / partial writes
#define DECLP(k) int p##k = g * PPB + k * 256 + threadIdx.x; \
                 float qx##k = qV[3*p##k+0], qy##k = qV[3*p##k+1], qz##k = qV[3*p##k+2]; \
                 float b1_##k = 1e30f, b2_##k = 1e30f; int i1_##k = 0x7fffffff;
    FOR4(DECLP)

    __syncthreads();
    #pragma unroll 4
    for (int i = 0; i < nfs; ++i) {
        float4 c = sh[i];                 // uniform addr -> LDS broadcast
#define UPD(k) { float dot_ = qx##k*c.x + qy##k*c.y + qz##k*c.z;   \
                 float key_ = c.w - 2.0f*dot_;                     \
                 bool  lt_  = key_ < b1_##k;                       \
                 float c2_  = fmaxf(key_, b1_##k);                 \
                 b2_##k = fminf(b2_##k, c2_);                      \
                 i1_##k = lt_ ? (fbase + i) : i1_##k;              \
                 b1_##k = lt_ ? key_ : b1_##k; }
        FOR4(UPD)
    }
#define STORE(k) { int fl_ = (b2_##k - b1_##k < MARGIN) ? 1 : 0;           \
                   pkey[(size_t)s*NP + p##k]   = b1_##k;                   \
                   pidxfl[(size_t)s*NP + p##k] = (fl_ << 16) | i1_##k; }
    FOR4(STORE)
}

// ---------------------------------------------------------------------------
// K1b: per point, lex-merge the split partials — EXACT R12 logic (global
// top-2 contained in union of split top-2s; winner-split ambiguity via flag
// bit). Exact np f64 d2 for winner -> outlier test.
// flag = winner-split-flag || (global r2 - bv < MARGIN) -> f64 repair.
// ---------------------------------------------------------------------------
__global__ __launch_bounds__(256) void k_finish(const float* __restrict__ qV,
                                                const double* __restrict__ ctr,
                                                const float* __restrict__ pkey,
                                                const int* __restrict__ pidxfl,
                                                float* __restrict__ out,
                                                int* __restrict__ fidx_ws,
                                                int* __restrict__ valid_ws,
                                                int* __restrict__ flag,
                                                int split) {
    int p = blockIdx.x * 256 + threadIdx.x;
    if (p >= NP) return;
    float bv = 1e30f, r2 = 1e30f; int bi = 0x7fffffff, wfl = 0;
    for (int s = 0; s < split; ++s) {
        float ov  = pkey[(size_t)s*NP + p];
        int   raw = pidxfl[(size_t)s*NP + p];
        int   oi  = raw & 0xFFFF;
        int   ofl = raw >> 16;
        bool win = (ov < bv) || (ov == bv && oi < bi);
        float loser = win ? bv : ov;
        r2 = fminf(r2, loser);
        bv  = win ? ov  : bv;
        bi  = win ? oi  : bi;
        wfl = win ? ofl : wfl;
    }
    flag[p] = (wfl || (r2 - bv < MARGIN)) ? 1 : 0;
    // exact np d2 for the winning face (f64)
    const double4* ctr4 = (const double4*)ctr;
    double4 c = ctr4[bi];
    double qx = (double)qV[3*p+0], qy = (double)qV[3*p+1], qz = (double)qV[3*p+2];
    double dot = qx*c.x + qy*c.y + qz*c.z;
    double qq  = qx*qx + qy*qy + qz*qz;
    double d2  = (qq - 2.0*dot) + c.w;
    int outlier = (d2 > 0.1) ? 1 : 0;
    fidx_ws[p]  = bi;
    valid_ws[p] = 1 - outlier;
    out[p]        = (float)bi;               // output 0: spt_fidx
    out[3*NP + p] = outlier ? 1.0f : 0.0f;   // output 2: outlier_mask
}

// ---------------------------------------------------------------------------
// K1c: exact f64 repair for flagged points — R6/R12's proven kernel.
// Full f64-key rescan, lex (key,idx); one block per point, unflagged blocks
// exit immediately.
// ---------------------------------------------------------------------------
__global__ __launch_bounds__(256) void k_repair(const float* __restrict__ qV,
                                                const double* __restrict__ ctr,
                                                const int* __restrict__ flag,
                                                float* __restrict__ out,
                                                int* __restrict__ fidx_ws,
                                                int* __restrict__ valid_ws) {
    int p = blockIdx.x;
    if (!flag[p]) return;
    double qx = (double)qV[3*p+0], qy = (double)qV[3*p+1], qz = (double)qV[3*p+2];
    double best = 1e300; int bidx = 0x7fffffff;
    const double4* ctr4 = (const double4*)ctr;
    for (int f = threadIdx.x; f < NF; f += 256) {
        double4 c = ctr4[f];
        double dot = qx*c.x + qy*c.y + qz*c.z;
        double key = c.w - 2.0*dot;
        if (key < best) { best = key; bidx = f; }   // ascending f: strict < = lex
    }
    #pragma unroll
    for (int off = 32; off > 0; off >>= 1) {
        double ov = __shfl_down(best, off);
        int    oi = __shfl_down(bidx, off);
        if (ov < best || (ov == best && oi < bidx)) { best = ov; bidx = oi; }
    }
    __shared__ double sv[4];
    __shared__ int    si[4];
    int wid = threadIdx.x >> 6, lane = threadIdx.x & 63;
    if (lane == 0) { sv[wid] = best; si[wid] = bidx; }
    __syncthreads();
    if (threadIdx.x == 0) {
        double bv = sv[0]; int bi = si[0];
        for (int w2 = 1; w2 < 4; ++w2) {
            double ov = sv[w2]; int oi = si[w2];
            if (ov < bv || (ov == bv && oi < bi)) { bv = ov; bi = oi; }
        }
        double4 c = ctr4[bi];
        double dot = qx*c.x + qy*c.y + qz*c.z;
        double qq  = qx*qx + qy*qy + qz*qz;
        double d2  = (qq - 2.0*dot) + c.w;
        int outlier = (d2 > 0.1) ? 1 : 0;
        fidx_ws[p]  = bi;
        valid_ws[p] = 1 - outlier;
        out[p]        = (float)bi;
        out[3*NP + p] = outlier ? 1.0f : 0.0f;
    }
}

// ---------------------------------------------------------------------------
// K2: denom = max(#valid, 1)
// ---------------------------------------------------------------------------
__global__ __launch_bounds__(256) void k_denom(const int* __restrict__ valid_ws,
                                               double* __restrict__ denom) {
    __shared__ int s[256];
    int acc = 0;
    for (int i = threadIdx.x; i < NP; i += 256) acc += valid_ws[i];
    s[threadIdx.x] = acc;
    __syncthreads();
    for (int off = 128; off > 0; off >>= 1) {
        if (threadIdx.x < off) s[threadIdx.x] += s[threadIdx.x + off];
        __syncthreads();
    }
    if (threadIdx.x == 0) {
        double d = (double)s[0];
        denom[0] = d > 1.0 ? d : 1.0;
    }
}

// ---------------------------------------------------------------------------
// K3: per-point 2x50-step Adagrad — BIT-IDENTICAL to the round-4 passing
// version (slim vw margin; do not perturb).
// ---------------------------------------------------------------------------
__global__ __launch_bounds__(256) void k_opt(const float* __restrict__ qV,
                                             const float* __restrict__ qN,
                                             const float* __restrict__ mV,
                                             const int* __restrict__ mF,
                                             const float* __restrict__ mN,
                                             const int* __restrict__ fidx_ws,
                                             const int* __restrict__ valid_ws,
                                             const double* __restrict__ denomp,
                                             const double* __restrict__ clrtab,
                                             float* __restrict__ out) {
    int p = blockIdx.x * 256 + threadIdx.x;
    if (p >= NP) return;
    const float third = (float)(1.0/3.0);
    if (!valid_ws[p]) {            // outlier: keeps init barycentric coords
        out[NP + 2*p + 0] = third;
        out[NP + 2*p + 1] = third;
        return;
    }
    double inv_denom = 1.0 / denomp[0];
    int f = fidx_ws[p];
    int i0 = mF[3*f+0], i1 = mF[3*f+1], i2 = mF[3*f+2];

    double V0x = mV[3*i0+0], V0y = mV[3*i0+1], V0z = mV[3*i0+2];
    double V1x = mV[3*i1+0], V1y = mV[3*i1+1], V1z = mV[3*i1+2];
    double V2x = mV[3*i2+0], V2y = mV[3*i2+1], V2z = mV[3*i2+2];
    double N0x = mN[3*i0+0], N0y = mN[3*i0+1], N0z = mN[3*i0+2];
    double N1x = mN[3*i1+0], N1y = mN[3*i1+1], N1z = mN[3*i1+2];
    double N2x = mN[3*i2+0], N2y = mN[3*i2+1], N2z = mN[3*i2+2];
    double qx  = qV[3*p+0],  qy  = qV[3*p+1],  qz  = qV[3*p+2];
    double qnx = qN[3*p+0],  qny = qN[3*p+1],  qnz = qN[3*p+2];

    double Eux = V0x - V2x, Euy = V0y - V2y, Euz = V0z - V2z;  // dcV/du
    double Ewx = V1x - V2x, Ewy = V1y - V2y, Ewz = V1z - V2z;  // dcV/dw
    double Fux = N0x - N2x, Fuy = N0y - N2y, Fuz = N0z - N2z;  // dn_raw/du
    double Fwx = N1x - N2x, Fwy = N1y - N2y, Fwz = N1z - N2z;  // dn_raw/dw
    double Kx  = V2x - qx,  Ky  = V2y - qy,  Kz  = V2z - qz;   // cv - q at uu=ww=0

    double u = 1.0/3.0, w = 1.0/3.0;
    double alpha = 1.0;
    for (int outer = 0; outer < 2; ++outer) {
        double du = 0.0, dw = 0.0, su = 0.0, sw = 0.0;
        for (int it = 0; it < 50; ++it) {
            double uu = u + du, ww = w + dw;
            // position term: rv = cv - q = uu*Eu + ww*Ew + K
            double rvx = uu*Eux + ww*Ewx + Kx;
            double rvy = uu*Euy + ww*Ewy + Ky;
            double rvz = uu*Euz + ww*Ewz + Kz;
            double L2v = rvx*rvx + rvy*rvy + rvz*rvz;
            double invLv = rsqrt(L2v);
            double gu = (rvx*Eux + rvy*Euy + rvz*Euz) * invLv;
            double gw = (rvx*Ewx + rvy*Ewy + rvz*Ewz) * invLv;
            // normal term: n = uu*Fu + ww*Fw + N2
            double nx = uu*Fux + ww*Fwx + N2x;
            double ny = uu*Fuy + ww*Fwy + N2y;
            double nz = uu*Fuz + ww*Fwz + N2z;
            double m2 = nx*nx + ny*ny + nz*nz;
            bool   mok = (m2 > 1e-24);           // <=> m > 1e-12
            double inv = mok ? rsqrt(m2) : 1e12; // 1/max(m,1e-12)
            double hx = nx*inv, hy = ny*inv, hz = nz*inv;
            double rnx = hx - qnx, rny = hy - qny, rnz = hz - qnz;
            double L2n = rnx*rnx + rny*rny + rnz*rnz;
            double invLn = rsqrt(L2n);
            double A_u = rnx*Fux + rny*Fuy + rnz*Fuz;
            double A_w = rnx*Fwx + rny*Fwy + rnz*Fwz;
            double B   = rnx*nx + rny*ny + rnz*nz;
            double C_u = nx*Fux + ny*Fuy + nz*Fuz;
            double C_w = nx*Fwx + ny*Fwy + nz*Fwz;
            // s = B/m^3 when m > eps else 0 (original dropped the term there)
            double s = mok ? ((B*inv)*inv)*inv : 0.0;
            double gnu = (A_u*inv - s*C_u) * invLn;
            double gnw = (A_w*inv - s*C_w) * invLn;
            gu = (gu + 0.01*gnu) * inv_denom;   // mask=1, masked-mean scaling
            gw = (gw + 0.01*gnw) * inv_denom;
            // Adagrad(lr=0.2, lr_decay=0.1)
            su += gu*gu; sw += gw*gw;
            double clr = clrtab[it];
            du -= clr * gu / (sqrt(su) + 1e-10);
            dw -= clr * gw / (sqrt(sw) + 1e-10);
        }
        u += du * alpha; w += dw * alpha;
        alpha *= 0.5;
    }
    out[NP + 2*p + 0] = (float)u;
    out[NP + 2*p + 1] = (float)w;
}

// ---------------------------------------------------------------------------
extern "C" void kernel_launch(void* const* d_in, const int* in_sizes, int n_in,
                              void* d_out, int out_size, void* d_ws, size_t ws_size,
                              hipStream_t stream) {
    const float* qV = (const float*)d_in[0];   // query_V [1,8192,3]
    const float* qN = (const float*)d_in[1];   // query_N [1,8192,3]
    const float* mV = (const float*)d_in[2];   // mesh_V  [16384,3]
    const int*   mF = (const int*)d_in[3];     // mesh_F  [16384,3] int32
    const float* mN = (const float*)d_in[4];   // mesh_N  [16384,3]
    float* out = (float*)d_out;                // fidx | vw | outlier_mask

    // pick largest SPLIT whose partial arrays fit in ws (deterministic per run)
    size_t base = (size_t)NF*4*8 + 8 + 50*8 + (size_t)NF*16 + 3*(size_t)NP*4;
    int split = 16;                                        // R12-proven footprint
    if (ws_size >= base + (size_t)64*NP*8) split = 64;
    else if (ws_size >= base + (size_t)32*NP*8) split = 32;
    int nfs = NF / split;

    double* ctr      = (double*)d_ws;                // NF*4 doubles (512 KB)
    double* denom    = ctr + (size_t)NF*4;           // 1 double
    double* clrtab   = denom + 1;                    // 50 doubles
    float4* ctrf     = (float4*)(clrtab + 50);       // NF float4 (256 KB)
    float*  pkey     = (float*)(ctrf + NF);          // split*NP f32
    int*    pidxfl   = (int*)(pkey + (size_t)split*NP); // split*NP ints
    int*    flag     = pidxfl + (size_t)split*NP;    // NP ints
    int*    fidx_ws  = flag + NP;                    // NP ints
    int*    valid_ws = fidx_ws + NP;                 // NP ints

    hipLaunchKernelGGL(k_centers,  dim3(NF/256),     dim3(256), 0, stream,
                       mV, mF, ctr, ctrf, clrtab);
    hipLaunchKernelGGL(k_knn_part, dim3(NPB*split),  dim3(256), 0, stream,
                       qV, ctrf, pkey, pidxfl, split, nfs);
    hipLaunchKernelGGL(k_finish,   dim3(NP/256),     dim3(256), 0, stream,
                       qV, ctr, pkey, pidxfl, out, fidx_ws, valid_ws, flag, split);
    hipLaunchKernelGGL(k_repair,   dim3(NP),         dim3(256), 0, stream,
                       qV, ctr, flag, out, fidx_ws, valid_ws);
    hipLaunchKernelGGL(k_denom,    dim3(1),          dim3(256), 0, stream, valid_ws, denom);
    hipLaunchKernelGGL(k_opt,      dim3(NP/256),     dim3(256), 0, stream,
                       qV, qN, mV, mF, mN, fidx_ws, valid_ws, denom, clrtab, out);
}

// Round 14
// 116.643 us; speedup vs baseline: 1.1444x; 1.1444x over previous
//
#include <hip/hip_runtime.h>
#include <math.h>

#define NP 8192
#define NF 16384
#define GQ 4                // points per block (state ~36 VGPR: no spill tier risk)
#define MARGIN 1e-5f        // f32 key abs-error ~3e-6; proven bit-exact R6/R12/R13

// ---------------------------------------------------------------------------
// K0: face centers: f64 (cx,cy,cz,|c|^2) for exact d2/repair, f32 copy for
// the fast scan, plus Adagrad clr table. np: c=(v0+v1+v2)/3 in f64.
// ---------------------------------------------------------------------------
__global__ __launch_bounds__(256) void k_centers(const float* __restrict__ mV,
                                                 const int* __restrict__ mF,
                                                 double* __restrict__ ctr,
                                                 float4* __restrict__ ctrf,
                                                 double* __restrict__ clrtab) {
    if (blockIdx.x == 0 && threadIdx.x < 50) {
        clrtab[threadIdx.x] = 0.2 / (1.0 + (double)threadIdx.x * 0.1);
    }
    int f = blockIdx.x * 256 + threadIdx.x;
    if (f >= NF) return;
    int i0 = mF[3*f+0], i1 = mF[3*f+1], i2 = mF[3*f+2];
    double cx = ((double)mV[3*i0+0] + (double)mV[3*i1+0] + (double)mV[3*i2+0]) / 3.0;
    double cy = ((double)mV[3*i0+1] + (double)mV[3*i1+1] + (double)mV[3*i2+1]) / 3.0;
    double cz = ((double)mV[3*i0+2] + (double)mV[3*i1+2] + (double)mV[3*i2+2]) / 3.0;
    double cc = cx*cx + cy*cy + cz*cz;
    ctr[4*f+0] = cx; ctr[4*f+1] = cy; ctr[4*f+2] = cz; ctr[4*f+3] = cc;
    ctrf[f] = make_float4((float)cx, (float)cy, (float)cz, (float)cc);
}

// ---------------------------------------------------------------------------
// K1: MONOLITHIC f32 1-NN with inline exact-f64 repair (R11's 4-launch
// structure — the split pipelines' ~30µs tax is gone). GQ=4 points/block,
// 2048 blocks = 8 waves/SIMD (2x R11), coalesced float4 loads (1/2 R11's
// bytes). Top-2 tracked; gap < MARGIN => whole block re-runs the exact R11
// f64 lex scan for that point (block-uniform branch, ~1µs). Unflagged
// winners provably equal the f64 argmin (error bound << MARGIN; scheme
// bit-exact-proven R6/R12/R13). Winner d2/outlier always exact f64.
// ---------------------------------------------------------------------------
__global__ __launch_bounds__(256) void k_knn(const float* __restrict__ qV,
                                             const float4* __restrict__ ctrf,
                                             const double* __restrict__ ctr,
                                             float* __restrict__ out,
                                             int* __restrict__ fidx_ws,
                                             int* __restrict__ valid_ws) {
    int pbase = blockIdx.x * GQ;
    float qx[GQ], qy[GQ], qz[GQ];
    #pragma unroll
    for (int g = 0; g < GQ; ++g) {
        int p = pbase + g;
        qx[g] = qV[3*p+0]; qy[g] = qV[3*p+1]; qz[g] = qV[3*p+2];
    }
    float b1[GQ], b2[GQ]; int i1[GQ];
    #pragma unroll
    for (int g = 0; g < GQ; ++g) { b1[g] = 1e30f; b2[g] = 1e30f; i1[g] = 0x7fffffff; }

    #pragma unroll 2
    for (int f = threadIdx.x; f < NF; f += 256) {
        float4 c = ctrf[f];                       // coalesced 1KB/wave
        #pragma unroll
        for (int g = 0; g < GQ; ++g) {
            float dot = qx[g]*c.x + qy[g]*c.y + qz[g]*c.z;
            float key = c.w - 2.0f*dot;
            bool  lt  = key < b1[g];
            float cand2 = fmaxf(key, b1[g]);      // loser of (key, b1)
            b2[g] = fminf(b2[g], cand2);
            i1[g] = lt ? f : i1[g];               // f ascends: strict < = lex
            b1[g] = lt ? key : b1[g];
        }
    }
    // wave (64-lane) top-2 merge, lex (b1,i1) for the winner
    #pragma unroll
    for (int off = 32; off > 0; off >>= 1) {
        #pragma unroll
        for (int g = 0; g < GQ; ++g) {
            float ob1 = __shfl_down(b1[g], off);
            int   oi1 = __shfl_down(i1[g], off);
            float ob2 = __shfl_down(b2[g], off);
            bool win = (ob1 < b1[g]) || (ob1 == b1[g] && oi1 < i1[g]);
            float loser = win ? b1[g] : ob1;
            b1[g] = win ? ob1 : b1[g];
            i1[g] = win ? oi1 : i1[g];
            b2[g] = fminf(loser, fminf(ob2, b2[g]));
        }
    }
    __shared__ float sv1[4][GQ], sv2[4][GQ];
    __shared__ int   si1[4][GQ];
    __shared__ int   rbi[GQ];
    __shared__ int   rfl[GQ];
    int wid = threadIdx.x >> 6, lane = threadIdx.x & 63;
    if (lane == 0) {
        #pragma unroll
        for (int g = 0; g < GQ; ++g) { sv1[wid][g] = b1[g]; si1[wid][g] = i1[g]; sv2[wid][g] = b2[g]; }
    }
    __syncthreads();
    if (threadIdx.x == 0) {
        for (int g = 0; g < GQ; ++g) {
            float bv = sv1[0][g], r2 = sv2[0][g]; int bi = si1[0][g];
            for (int w2 = 1; w2 < 4; ++w2) {
                float ob1 = sv1[w2][g], ob2 = sv2[w2][g]; int oi1 = si1[w2][g];
                bool win = (ob1 < bv) || (ob1 == bv && oi1 < bi);
                float loser = win ? bv : ob1;
                bv = win ? ob1 : bv;
                bi = win ? oi1 : bi;
                r2 = fminf(loser, fminf(ob2, r2));
            }
            rbi[g] = bi;
            rfl[g] = (r2 - bv < MARGIN) ? 1 : 0;
        }
    }
    __syncthreads();

    // inline exact-f64 repair for flagged points (block-uniform branches)
    const double4* ctr4 = (const double4*)ctr;
    __shared__ double dsv[4];
    __shared__ int    dsi[4];
    for (int g = 0; g < GQ; ++g) {
        if (!rfl[g]) continue;                    // uniform (LDS) -> safe w/ syncs
        int p = pbase + g;
        double dqx = (double)qV[3*p+0], dqy = (double)qV[3*p+1], dqz = (double)qV[3*p+2];
        double best = 1e300; int bidx = 0x7fffffff;
        for (int f = threadIdx.x; f < NF; f += 256) {
            double4 c = ctr4[f];
            double dot = dqx*c.x + dqy*c.y + dqz*c.z;
            double key = c.w - 2.0*dot;
            if (key < best) { best = key; bidx = f; }
        }
        #pragma unroll
        for (int off = 32; off > 0; off >>= 1) {
            double ov = __shfl_down(best, off);
            int    oi = __shfl_down(bidx, off);
            if (ov < best || (ov == best && oi < bidx)) { best = ov; bidx = oi; }
        }
        if (lane == 0) { dsv[wid] = best; dsi[wid] = bidx; }
        __syncthreads();
        if (threadIdx.x == 0) {
            double bv = dsv[0]; int bi = dsi[0];
            for (int w2 = 1; w2 < 4; ++w2) {
                double ov = dsv[w2]; int oi = dsi[w2];
                if (ov < bv || (ov == bv && oi < bi)) { bv = ov; bi = oi; }
            }
            rbi[g] = bi;                          // exact f64 winner
        }
        __syncthreads();
    }

    // epilogue: exact np f64 d2 for each winner -> outlier test -> outputs
    if (threadIdx.x == 0) {
        for (int g = 0; g < GQ; ++g) {
            int p = pbase + g;
            int bi = rbi[g];
            double4 c = ctr4[bi];
            double dqx = (double)qV[3*p+0], dqy = (double)qV[3*p+1], dqz = (double)qV[3*p+2];
            double dot = dqx*c.x + dqy*c.y + dqz*c.z;
            double qq  = dqx*dqx + dqy*dqy + dqz*dqz;
            double d2  = (qq - 2.0*dot) + c.w;
            int outlier = (d2 > 0.1) ? 1 : 0;
            fidx_ws[p]  = bi;
            valid_ws[p] = 1 - outlier;
            out[p]        = (float)bi;               // output 0: spt_fidx
            out[3*NP + p] = outlier ? 1.0f : 0.0f;   // output 2: outlier_mask
        }
    }
}

// ---------------------------------------------------------------------------
// K2: denom = max(#valid, 1)
// ---------------------------------------------------------------------------
__global__ __launch_bounds__(256) void k_denom(const int* __restrict__ valid_ws,
                                               double* __restrict__ denom) {
    __shared__ int s[256];
    int acc = 0;
    for (int i = threadIdx.x; i < NP; i += 256) acc += valid_ws[i];
    s[threadIdx.x] = acc;
    __syncthreads();
    for (int off = 128; off > 0; off >>= 1) {
        if (threadIdx.x < off) s[threadIdx.x] += s[threadIdx.x + off];
        __syncthreads();
    }
    if (threadIdx.x == 0) {
        double d = (double)s[0];
        denom[0] = d > 1.0 ? d : 1.0;
    }
}

// ---------------------------------------------------------------------------
// K3: per-point 2x50-step Adagrad — BIT-IDENTICAL to the round-4 passing
// version (slim vw margin; do not perturb).
// ---------------------------------------------------------------------------
__global__ __launch_bounds__(256) void k_opt(const float* __restrict__ qV,
                                             const float* __restrict__ qN,
                                             const float* __restrict__ mV,
                                             const int* __restrict__ mF,
                                             const float* __restrict__ mN,
                                             const int* __restrict__ fidx_ws,
                                             const int* __restrict__ valid_ws,
                                             const double* __restrict__ denomp,
                                             const double* __restrict__ clrtab,
                                             float* __restrict__ out) {
    int p = blockIdx.x * 256 + threadIdx.x;
    if (p >= NP) return;
    const float third = (float)(1.0/3.0);
    if (!valid_ws[p]) {            // outlier: keeps init barycentric coords
        out[NP + 2*p + 0] = third;
        out[NP + 2*p + 1] = third;
        return;
    }
    double inv_denom = 1.0 / denomp[0];
    int f = fidx_ws[p];
    int i0 = mF[3*f+0], i1 = mF[3*f+1], i2 = mF[3*f+2];

    double V0x = mV[3*i0+0], V0y = mV[3*i0+1], V0z = mV[3*i0+2];
    double V1x = mV[3*i1+0], V1y = mV[3*i1+1], V1z = mV[3*i1+2];
    double V2x = mV[3*i2+0], V2y = mV[3*i2+1], V2z = mV[3*i2+2];
    double N0x = mN[3*i0+0], N0y = mN[3*i0+1], N0z = mN[3*i0+2];
    double N1x = mN[3*i1+0], N1y = mN[3*i1+1], N1z = mN[3*i1+2];
    double N2x = mN[3*i2+0], N2y = mN[3*i2+1], N2z = mN[3*i2+2];
    double qx  = qV[3*p+0],  qy  = qV[3*p+1],  qz  = qV[3*p+2];
    double qnx = qN[3*p+0],  qny = qN[3*p+1],  qnz = qN[3*p+2];

    double Eux = V0x - V2x, Euy = V0y - V2y, Euz = V0z - V2z;  // dcV/du
    double Ewx = V1x - V2x, Ewy = V1y - V2y, Ewz = V1z - V2z;  // dcV/dw
    double Fux = N0x - N2x, Fuy = N0y - N2y, Fuz = N0z - N2z;  // dn_raw/du
    double Fwx = N1x - N2x, Fwy = N1y - N2y, Fwz = N1z - N2z;  // dn_raw/dw
    double Kx  = V2x - qx,  Ky  = V2y - qy,  Kz  = V2z - qz;   // cv - q at uu=ww=0

    double u = 1.0/3.0, w = 1.0/3.0;
    double alpha = 1.0;
    for (int outer = 0; outer < 2; ++outer) {
        double du = 0.0, dw = 0.0, su = 0.0, sw = 0.0;
        for (int it = 0; it < 50; ++it) {
            double uu = u + du, ww = w + dw;
            // position term: rv = cv - q = uu*Eu + ww*Ew + K
            double rvx = uu*Eux + ww*Ewx + Kx;
            double rvy = uu*Euy + ww*Ewy + Ky;
            double rvz = uu*Euz + ww*Ewz + Kz;
            double L2v = rvx*rvx + rvy*rvy + rvz*rvz;
            double invLv = rsqrt(L2v);
            double gu = (rvx*Eux + rvy*Euy + rvz*Euz) * invLv;
            double gw = (rvx*Ewx + rvy*Ewy + rvz*Ewz) * invLv;
            // normal term: n = uu*Fu + ww*Fw + N2
            double nx = uu*Fux + ww*Fwx + N2x;
            double ny = uu*Fuy + ww*Fwy + N2y;
            double nz = uu*Fuz + ww*Fwz + N2z;
            double m2 = nx*nx + ny*ny + nz*nz;
            bool   mok = (m2 > 1e-24);           // <=> m > 1e-12
            double inv = mok ? rsqrt(m2) : 1e12; // 1/max(m,1e-12)
            double hx = nx*inv, hy = ny*inv, hz = nz*inv;
            double rnx = hx - qnx, rny = hy - qny, rnz = hz - qnz;
            double L2n = rnx*rnx + rny*rny + rnz*rnz;
            double invLn = rsqrt(L2n);
            double A_u = rnx*Fux + rny*Fuy + rnz*Fuz;
            double A_w = rnx*Fwx + rny*Fwy + rnz*Fwz;
            double B   = rnx*nx + rny*ny + rnz*nz;
            double C_u = nx*Fux + ny*Fuy + nz*Fuz;
            double C_w = nx*Fwx + ny*Fwy + nz*Fwz;
            // s = B/m^3 when m > eps else 0 (original dropped the term there)
            double s = mok ? ((B*inv)*inv)*inv : 0.0;
            double gnu = (A_u*inv - s*C_u) * invLn;
            double gnw = (A_w*inv - s*C_w) * invLn;
            gu = (gu + 0.01*gnu) * inv_denom;   // mask=1, masked-mean scaling
            gw = (gw + 0.01*gnw) * inv_denom;
            // Adagrad(lr=0.2, lr_decay=0.1)
            su += gu*gu; sw += gw*gw;
            double clr = clrtab[it];
            du -= clr * gu / (sqrt(su) + 1e-10);
            dw -= clr * gw / (sqrt(sw) + 1e-10);
        }
        u += du * alpha; w += dw * alpha;
        alpha *= 0.5;
    }
    out[NP + 2*p + 0] = (float)u;
    out[NP + 2*p + 1] = (float)w;
}

// ---------------------------------------------------------------------------
extern "C" void kernel_launch(void* const* d_in, const int* in_sizes, int n_in,
                              void* d_out, int out_size, void* d_ws, size_t ws_size,
                              hipStream_t stream) {
    const float* qV = (const float*)d_in[0];   // query_V [1,8192,3]
    const float* qN = (const float*)d_in[1];   // query_N [1,8192,3]
    const float* mV = (const float*)d_in[2];   // mesh_V  [16384,3]
    const int*   mF = (const int*)d_in[3];     // mesh_F  [16384,3] int32
    const float* mN = (const float*)d_in[4];   // mesh_N  [16384,3]
    float* out = (float*)d_out;                // fidx | vw | outlier_mask

    double* ctr      = (double*)d_ws;              // NF*4 doubles (512 KB)
    double* denom    = ctr + (size_t)NF*4;         // 1 double
    double* clrtab   = denom + 1;                  // 50 doubles
    float4* ctrf     = (float4*)(clrtab + 50);     // NF float4 (256 KB)
    int*    fidx_ws  = (int*)(ctrf + NF);          // NP ints
    int*    valid_ws = fidx_ws + NP;               // NP ints

    hipLaunchKernelGGL(k_centers, dim3(NF/256), dim3(256), 0, stream,
                       mV, mF, ctr, ctrf, clrtab);
    hipLaunchKernelGGL(k_knn,     dim3(NP/GQ),  dim3(256), 0, stream,
                       qV, ctrf, ctr, out, fidx_ws, valid_ws);
    hipLaunchKernelGGL(k_denom,   dim3(1),      dim3(256), 0, stream, valid_ws, denom);
    hipLaunchKernelGGL(k_opt,     dim3(NP/256), dim3(256), 0, stream,
                       qV, qN, mV, mF, mN, fidx_ws, valid_ws, denom, clrtab, out);
}